// Round 1
// baseline (363.845 us; speedup 1.0000x reference)
//
#include <hip/hip_runtime.h>
#include <cstdint>

#define DIM   768
#define HEADS 12
#define HDIM  64
#define BATCH 4
#define SEQ   2048
#define MROWS (BATCH*SEQ)   // 8192

typedef __bf16 bf16;
typedef __bf16 bf16x4_t __attribute__((ext_vector_type(4)));
typedef __bf16 bf16x8_t __attribute__((ext_vector_type(8)));
typedef float  f32x4_t  __attribute__((ext_vector_type(4)));

// ---------------- fp32 -> bf16 cast, 4 elems/thread ----------------
__global__ void cast_bf16_kernel(const float* __restrict__ src, bf16* __restrict__ dst, int n4) {
    int i = blockIdx.x * blockDim.x + threadIdx.x;
    if (i >= n4) return;
    const float4 v = reinterpret_cast<const float4*>(src)[i];
    bf16x4_t o;
    o[0] = (bf16)v.x; o[1] = (bf16)v.y; o[2] = (bf16)v.z; o[3] = (bf16)v.w;
    reinterpret_cast<bf16x4_t*>(dst)[i] = o;
}

// async global->LDS, 16B per lane. LDS dest must be wave-uniform base + lane*16.
__device__ __forceinline__ void gload_lds16(const bf16* g, bf16* l) {
    __builtin_amdgcn_global_load_lds((const __attribute__((address_space(1))) void*)g,
                                     (__attribute__((address_space(3))) void*)l, 16, 0, 0);
}

// ---------------- QKV projection GEMM ----------------
// Y = X @ W^T ; X [8192,768] bf16, W [768,768] bf16 (row-major [n,k] => B^T gemm)
// z=0 -> Q [B,H,N,64], z=1 -> K [B,H,N,64], z=2 -> V transposed [B,H,64,N]
__global__ __launch_bounds__(256, 2) void qkv_gemm(
        const bf16* __restrict__ X,
        const bf16* __restrict__ Wq, const bf16* __restrict__ Wk, const bf16* __restrict__ Wv,
        bf16* __restrict__ Q, bf16* __restrict__ Kd, bf16* __restrict__ Vt)
{
    __shared__ bf16 As[128*32];
    __shared__ bf16 Bs[128*32];
    const int tid  = threadIdx.x;
    const int z    = blockIdx.z;
    const bf16* W  = (z == 0) ? Wq : (z == 1 ? Wk : Wv);
    const int n0   = blockIdx.x * 128;
    const int m0   = blockIdx.y * 128;
    const int lane = tid & 63;
    const int w    = tid >> 6;
    const int wm   = (w & 1) * 64, wn = (w >> 1) * 64;
    const int lr   = lane & 15, quad = lane >> 4;

    f32x4_t acc[4][4] = {};

    for (int kk = 0; kk < DIM; kk += 32) {
        #pragma unroll
        for (int i = 0; i < 2; ++i) {
            int c = tid + i * 256;          // 0..511, wave-contiguous
            int row = c >> 2, ko = (c & 3) * 8;
            gload_lds16(X + (size_t)(m0 + row) * DIM + kk + ko, &As[row * 32 + ko]);
            gload_lds16(W + (size_t)(n0 + row) * DIM + kk + ko, &Bs[row * 32 + ko]);
        }
        __syncthreads();
        bf16x8_t af[4], bfr[4];
        #pragma unroll
        for (int i = 0; i < 4; ++i)
            af[i] = *reinterpret_cast<const bf16x8_t*>(&As[(wm + i * 16 + lr) * 32 + quad * 8]);
        #pragma unroll
        for (int j = 0; j < 4; ++j)
            bfr[j] = *reinterpret_cast<const bf16x8_t*>(&Bs[(wn + j * 16 + lr) * 32 + quad * 8]);
        #pragma unroll
        for (int i = 0; i < 4; ++i)
            #pragma unroll
            for (int j = 0; j < 4; ++j)
                acc[i][j] = __builtin_amdgcn_mfma_f32_16x16x32_bf16(af[i], bfr[j], acc[i][j], 0, 0, 0);
        __syncthreads();
    }

    // epilogue: C layout col=lane&15, row=quad*4+reg
    #pragma unroll
    for (int i = 0; i < 4; ++i) {
        int mbase = m0 + wm + i * 16 + quad * 4;
        #pragma unroll
        for (int j = 0; j < 4; ++j) {
            int n = n0 + wn + j * 16 + lr;
            int h = n >> 6, d = n & 63;
            #pragma unroll
            for (int r = 0; r < 4; ++r) {
                int m = mbase + r;
                int b = m >> 11, row = m & 2047;
                bf16 v = (bf16)acc[i][j][r];
                if (z < 2) {
                    bf16* dst = (z == 0) ? Q : Kd;
                    dst[(((size_t)b * HEADS + h) * SEQ + row) * HDIM + d] = v;
                } else {
                    Vt[(((size_t)b * HEADS + h) * HDIM + d) * SEQ + row] = v;
                }
            }
        }
    }
}

// ---------------- output projection GEMM (+bias, fp32 out) ----------------
__global__ __launch_bounds__(256, 2) void out_gemm(
        const bf16* __restrict__ A,       // [8192,768] bf16
        const bf16* __restrict__ W,       // [768,768] bf16
        const float* __restrict__ bias,   // [768]
        float* __restrict__ out)          // [8192,768] f32
{
    __shared__ bf16 As[128*32];
    __shared__ bf16 Bs[128*32];
    const int tid  = threadIdx.x;
    const int n0   = blockIdx.x * 128;
    const int m0   = blockIdx.y * 128;
    const int lane = tid & 63;
    const int w    = tid >> 6;
    const int wm   = (w & 1) * 64, wn = (w >> 1) * 64;
    const int lr   = lane & 15, quad = lane >> 4;

    f32x4_t acc[4][4] = {};

    for (int kk = 0; kk < DIM; kk += 32) {
        #pragma unroll
        for (int i = 0; i < 2; ++i) {
            int c = tid + i * 256;
            int row = c >> 2, ko = (c & 3) * 8;
            gload_lds16(A + (size_t)(m0 + row) * DIM + kk + ko, &As[row * 32 + ko]);
            gload_lds16(W + (size_t)(n0 + row) * DIM + kk + ko, &Bs[row * 32 + ko]);
        }
        __syncthreads();
        bf16x8_t af[4], bfr[4];
        #pragma unroll
        for (int i = 0; i < 4; ++i)
            af[i] = *reinterpret_cast<const bf16x8_t*>(&As[(wm + i * 16 + lr) * 32 + quad * 8]);
        #pragma unroll
        for (int j = 0; j < 4; ++j)
            bfr[j] = *reinterpret_cast<const bf16x8_t*>(&Bs[(wn + j * 16 + lr) * 32 + quad * 8]);
        #pragma unroll
        for (int i = 0; i < 4; ++i)
            #pragma unroll
            for (int j = 0; j < 4; ++j)
                acc[i][j] = __builtin_amdgcn_mfma_f32_16x16x32_bf16(af[i], bfr[j], acc[i][j], 0, 0, 0);
        __syncthreads();
    }

    #pragma unroll
    for (int i = 0; i < 4; ++i) {
        int mbase = m0 + wm + i * 16 + quad * 4;
        #pragma unroll
        for (int j = 0; j < 4; ++j) {
            int n = n0 + wn + j * 16 + lr;
            float bv = bias[n];
            #pragma unroll
            for (int r = 0; r < 4; ++r) {
                int m = mbase + r;
                out[(size_t)m * DIM + n] = acc[i][j][r] + bv;
            }
        }
    }
}

// ---------------- flash attention (no-max online softmax) ----------------
// Q,K: [BH, N, 64] bf16 ; Vt: [BH, 64, N] bf16 ; Ab out: [B, N, 768] bf16
__global__ __launch_bounds__(256, 2) void attn_kernel(
        const bf16* __restrict__ Q, const bf16* __restrict__ Kd,
        const bf16* __restrict__ Vt, bf16* __restrict__ Ab)
{
    __shared__ bf16 Qs[64*64];
    __shared__ bf16 Ks[64*64];
    __shared__ bf16 Vs[64*64];     // Vt tile [d][k]
    __shared__ bf16 Ps[4][16*64];  // per-wave P round-trip (C-layout -> A-layout)

    const int tid  = threadIdx.x;
    const int bh   = blockIdx.y;            // 0..47
    const int b    = bh / HEADS, h = bh % HEADS;
    const int q0   = blockIdx.x * 64;
    const int lane = tid & 63, w = tid >> 6;
    const int lr   = lane & 15, quad = lane >> 4;

    const size_t qkbase = (size_t)bh * SEQ * HDIM;
    const size_t vbase  = (size_t)bh * HDIM * SEQ;

    // stage Q tile [64 q][64 d] once
    #pragma unroll
    for (int i = 0; i < 2; ++i) {
        int c = tid + i * 256;
        int row = c >> 3, ko = (c & 7) * 8;
        gload_lds16(Q + qkbase + (size_t)(q0 + row) * HDIM + ko, &Qs[row * 64 + ko]);
    }

    f32x4_t oacc[4] = {};
    float lsum[4] = {0.f, 0.f, 0.f, 0.f};

    for (int kt = 0; kt < SEQ; kt += 64) {
        #pragma unroll
        for (int i = 0; i < 2; ++i) {
            int c = tid + i * 256;
            int row = c >> 3, ko = (c & 7) * 8;
            gload_lds16(Kd + qkbase + (size_t)(kt + row) * HDIM + ko, &Ks[row * 64 + ko]);
            gload_lds16(Vt + vbase  + (size_t)row * SEQ + kt + ko,    &Vs[row * 64 + ko]);
        }
        __syncthreads();

        // S = Q K^T for this wave's 16 query rows
        f32x4_t sacc[4] = {};
        #pragma unroll
        for (int ks = 0; ks < 2; ++ks) {
            bf16x8_t aq = *reinterpret_cast<const bf16x8_t*>(&Qs[(w * 16 + lr) * 64 + ks * 32 + quad * 8]);
            #pragma unroll
            for (int j = 0; j < 4; ++j) {
                bf16x8_t bk = *reinterpret_cast<const bf16x8_t*>(&Ks[(j * 16 + lr) * 64 + ks * 32 + quad * 8]);
                sacc[j] = __builtin_amdgcn_mfma_f32_16x16x32_bf16(aq, bk, sacc[j], 0, 0, 0);
            }
        }

        // p = exp(s/8); row-sums; write P to LDS in [row][col] layout
        float rs[4] = {0.f, 0.f, 0.f, 0.f};
        #pragma unroll
        for (int j = 0; j < 4; ++j) {
            #pragma unroll
            for (int r = 0; r < 4; ++r) {
                float p = __expf(sacc[j][r] * 0.125f);
                rs[r] += p;
                Ps[w][(quad * 4 + r) * 64 + j * 16 + lr] = (bf16)p;
            }
        }
        #pragma unroll
        for (int r = 0; r < 4; ++r) {
            float t = rs[r];
            t += __shfl_xor(t, 1);
            t += __shfl_xor(t, 2);
            t += __shfl_xor(t, 4);
            t += __shfl_xor(t, 8);
            lsum[r] += t;
        }
        __syncthreads();  // Ps cross-lane visibility

        // O += P @ V  (Vt rows are k-contiguous)
        #pragma unroll
        for (int ks = 0; ks < 2; ++ks) {
            bf16x8_t ap = *reinterpret_cast<const bf16x8_t*>(&Ps[w][lr * 64 + ks * 32 + quad * 8]);
            #pragma unroll
            for (int j = 0; j < 4; ++j) {
                bf16x8_t bv = *reinterpret_cast<const bf16x8_t*>(&Vs[(j * 16 + lr) * 64 + ks * 32 + quad * 8]);
                oacc[j] = __builtin_amdgcn_mfma_f32_16x16x32_bf16(ap, bv, oacc[j], 0, 0, 0);
            }
        }
        __syncthreads();  // protect Ks/Vs before next stage
    }

    // normalize and store to [B, N, DIM] (head-interleaved for the final GEMM)
    #pragma unroll
    for (int j = 0; j < 4; ++j) {
        #pragma unroll
        for (int r = 0; r < 4; ++r) {
            int q = q0 + w * 16 + quad * 4 + r;
            float v = oacc[j][r] / lsum[r];
            Ab[((size_t)b * SEQ + q) * DIM + h * HDIM + j * 16 + lr] = (bf16)v;
        }
    }
}

extern "C" void kernel_launch(void* const* d_in, const int* in_sizes, int n_in,
                              void* d_out, int out_size, void* d_ws, size_t ws_size,
                              hipStream_t stream) {
    (void)in_sizes; (void)n_in; (void)out_size; (void)ws_size;
    const float* x  = (const float*)d_in[0];
    const float* Wq = (const float*)d_in[1];
    const float* Wk = (const float*)d_in[2];
    const float* Wv = (const float*)d_in[3];
    const float* Wp = (const float*)d_in[4];
    const float* bp = (const float*)d_in[5];
    float* out = (float*)d_out;

    char* ws = (char*)d_ws;
    size_t off = 0;
    auto alloc = [&](size_t bytes) {
        void* p = ws + off;
        off += (bytes + 255) & ~(size_t)255;
        return p;
    };
    const size_t big = (size_t)MROWS * DIM * sizeof(bf16);   // 12.58 MB
    const size_t wsz = (size_t)DIM * DIM * sizeof(bf16);     // 1.18 MB
    bf16* Xb  = (bf16*)alloc(big);
    bf16* Qb  = (bf16*)alloc(big);
    bf16* Kb  = (bf16*)alloc(big);
    bf16* Vtb = (bf16*)alloc(big);
    bf16* Wqb = (bf16*)alloc(wsz);
    bf16* Wkb = (bf16*)alloc(wsz);
    bf16* Wvb = (bf16*)alloc(wsz);
    bf16* Wpb = (bf16*)alloc(wsz);
    bf16* Ab  = Xb;   // reuse: Xb dead after qkv_gemm

    const int x4 = MROWS * DIM / 4;
    cast_bf16_kernel<<<(x4 + 255) / 256, 256, 0, stream>>>(x, Xb, x4);
    const int w4 = DIM * DIM / 4;
    cast_bf16_kernel<<<(w4 + 255) / 256, 256, 0, stream>>>(Wq, Wqb, w4);
    cast_bf16_kernel<<<(w4 + 255) / 256, 256, 0, stream>>>(Wk, Wkb, w4);
    cast_bf16_kernel<<<(w4 + 255) / 256, 256, 0, stream>>>(Wv, Wvb, w4);
    cast_bf16_kernel<<<(w4 + 255) / 256, 256, 0, stream>>>(Wp, Wpb, w4);

    qkv_gemm<<<dim3(DIM / 128, MROWS / 128, 3), 256, 0, stream>>>(Xb, Wqb, Wkb, Wvb, Qb, Kb, Vtb);

    attn_kernel<<<dim3(SEQ / 64, BATCH * HEADS), 256, 0, stream>>>(Qb, Kb, Vtb, Ab);

    out_gemm<<<dim3(DIM / 128, MROWS / 128), 256, 0, stream>>>(Ab, Wpb, bp, out);
}

// Round 2
// 257.250 us; speedup vs baseline: 1.4144x; 1.4144x over previous
//
#include <hip/hip_runtime.h>
#include <cstdint>

#define DIM   768
#define HEADS 12
#define HDIM  64
#define BATCH 4
#define SEQ   2048
#define MROWS (BATCH*SEQ)   // 8192
#define PSTR  72            // Ps row stride (64 keys + 8 pad) -> conflict-free, 16B-aligned rows

typedef __bf16 bf16;
typedef __bf16 bf16x4_t __attribute__((ext_vector_type(4)));
typedef __bf16 bf16x8_t __attribute__((ext_vector_type(8)));
typedef float  f32x4_t  __attribute__((ext_vector_type(4)));

// ---------------- fp32 -> bf16 cast, 4 elems/thread ----------------
__global__ void cast_bf16_kernel(const float* __restrict__ src, bf16* __restrict__ dst, int n4) {
    int i = blockIdx.x * blockDim.x + threadIdx.x;
    if (i >= n4) return;
    const float4 v = reinterpret_cast<const float4*>(src)[i];
    bf16x4_t o;
    o[0] = (bf16)v.x; o[1] = (bf16)v.y; o[2] = (bf16)v.z; o[3] = (bf16)v.w;
    reinterpret_cast<bf16x4_t*>(dst)[i] = o;
}

// async global->LDS, 16B per lane. LDS dest is wave-uniform base + lane*16.
__device__ __forceinline__ void gload_lds16(const bf16* g, bf16* l) {
    __builtin_amdgcn_global_load_lds((const __attribute__((address_space(1))) void*)g,
                                     (__attribute__((address_space(3))) void*)l, 16, 0, 0);
}

// ---------------- QKV projection GEMM ----------------
__global__ __launch_bounds__(256, 2) void qkv_gemm(
        const bf16* __restrict__ X,
        const bf16* __restrict__ Wq, const bf16* __restrict__ Wk, const bf16* __restrict__ Wv,
        bf16* __restrict__ Q, bf16* __restrict__ Kd, bf16* __restrict__ Vt)
{
    __shared__ bf16 As[128*32];
    __shared__ bf16 Bs[128*32];
    const int tid  = threadIdx.x;
    const int z    = blockIdx.z;
    const bf16* W  = (z == 0) ? Wq : (z == 1 ? Wk : Wv);
    const int n0   = blockIdx.x * 128;
    const int m0   = blockIdx.y * 128;
    const int lane = tid & 63;
    const int w    = tid >> 6;
    const int wm   = (w & 1) * 64, wn = (w >> 1) * 64;
    const int lr   = lane & 15, quad = lane >> 4;

    f32x4_t acc[4][4] = {};

    for (int kk = 0; kk < DIM; kk += 32) {
        #pragma unroll
        for (int i = 0; i < 2; ++i) {
            int c = tid + i * 256;
            int row = c >> 2, ko = (c & 3) * 8;
            gload_lds16(X + (size_t)(m0 + row) * DIM + kk + ko, &As[row * 32 + ko]);
            gload_lds16(W + (size_t)(n0 + row) * DIM + kk + ko, &Bs[row * 32 + ko]);
        }
        __syncthreads();
        bf16x8_t af[4], bfr[4];
        #pragma unroll
        for (int i = 0; i < 4; ++i)
            af[i] = *reinterpret_cast<const bf16x8_t*>(&As[(wm + i * 16 + lr) * 32 + quad * 8]);
        #pragma unroll
        for (int j = 0; j < 4; ++j)
            bfr[j] = *reinterpret_cast<const bf16x8_t*>(&Bs[(wn + j * 16 + lr) * 32 + quad * 8]);
        #pragma unroll
        for (int i = 0; i < 4; ++i)
            #pragma unroll
            for (int j = 0; j < 4; ++j)
                acc[i][j] = __builtin_amdgcn_mfma_f32_16x16x32_bf16(af[i], bfr[j], acc[i][j], 0, 0, 0);
        __syncthreads();
    }

    #pragma unroll
    for (int i = 0; i < 4; ++i) {
        int mbase = m0 + wm + i * 16 + quad * 4;
        #pragma unroll
        for (int j = 0; j < 4; ++j) {
            int n = n0 + wn + j * 16 + lr;
            int h = n >> 6, d = n & 63;
            #pragma unroll
            for (int r = 0; r < 4; ++r) {
                int m = mbase + r;
                int b = m >> 11, row = m & 2047;
                bf16 v = (bf16)acc[i][j][r];
                if (z < 2) {
                    bf16* dst = (z == 0) ? Q : Kd;
                    dst[(((size_t)b * HEADS + h) * SEQ + row) * HDIM + d] = v;
                } else {
                    Vt[(((size_t)b * HEADS + h) * HDIM + d) * SEQ + row] = v;
                }
            }
        }
    }
}

// ---------------- output projection GEMM (+bias, fp32 out) ----------------
__global__ __launch_bounds__(256, 2) void out_gemm(
        const bf16* __restrict__ A,
        const bf16* __restrict__ W,
        const float* __restrict__ bias,
        float* __restrict__ out)
{
    __shared__ bf16 As[128*32];
    __shared__ bf16 Bs[128*32];
    const int tid  = threadIdx.x;
    const int n0   = blockIdx.x * 128;
    const int m0   = blockIdx.y * 128;
    const int lane = tid & 63;
    const int w    = tid >> 6;
    const int wm   = (w & 1) * 64, wn = (w >> 1) * 64;
    const int lr   = lane & 15, quad = lane >> 4;

    f32x4_t acc[4][4] = {};

    for (int kk = 0; kk < DIM; kk += 32) {
        #pragma unroll
        for (int i = 0; i < 2; ++i) {
            int c = tid + i * 256;
            int row = c >> 2, ko = (c & 3) * 8;
            gload_lds16(A + (size_t)(m0 + row) * DIM + kk + ko, &As[row * 32 + ko]);
            gload_lds16(W + (size_t)(n0 + row) * DIM + kk + ko, &Bs[row * 32 + ko]);
        }
        __syncthreads();
        bf16x8_t af[4], bfr[4];
        #pragma unroll
        for (int i = 0; i < 4; ++i)
            af[i] = *reinterpret_cast<const bf16x8_t*>(&As[(wm + i * 16 + lr) * 32 + quad * 8]);
        #pragma unroll
        for (int j = 0; j < 4; ++j)
            bfr[j] = *reinterpret_cast<const bf16x8_t*>(&Bs[(wn + j * 16 + lr) * 32 + quad * 8]);
        #pragma unroll
        for (int i = 0; i < 4; ++i)
            #pragma unroll
            for (int j = 0; j < 4; ++j)
                acc[i][j] = __builtin_amdgcn_mfma_f32_16x16x32_bf16(af[i], bfr[j], acc[i][j], 0, 0, 0);
        __syncthreads();
    }

    #pragma unroll
    for (int i = 0; i < 4; ++i) {
        int mbase = m0 + wm + i * 16 + quad * 4;
        #pragma unroll
        for (int j = 0; j < 4; ++j) {
            int n = n0 + wn + j * 16 + lr;
            float bv = bias[n];
            #pragma unroll
            for (int r = 0; r < 4; ++r) {
                int m = mbase + r;
                out[(size_t)m * DIM + n] = acc[i][j][r] + bv;
            }
        }
    }
}

// ---------------- flash attention v2 ----------------
// Q-tile 128 (wave owns 32 queries, Q frags in registers), K-tile 64 double-buffered,
// S computed transposed (key=M, query=N) so P packs to LDS with b64 conflict-free writes,
// XOR chunk swizzle on all staged tiles -> conflict-free ds_read_b128.
__global__ __launch_bounds__(256, 2) void attn_kernel(
        const bf16* __restrict__ Q, const bf16* __restrict__ Kd,
        const bf16* __restrict__ Vt, bf16* __restrict__ Ab)
{
    __shared__ __align__(16) bf16 KV[2][2][64*64];   // [buf][K|V][row*64] swizzled
    __shared__ __align__(16) bf16 Ps[4][32*PSTR];    // wave-private P [query][key]

    const int tid  = threadIdx.x;
    const int bh   = blockIdx.y;
    const int b    = bh / HEADS, h = bh % HEADS;
    const int q0   = blockIdx.x * 128;
    const int lane = tid & 63, w = tid >> 6;
    const int lr   = lane & 15, quad = lane >> 4;
    const int wq   = w * 32;

    const size_t qkbase = (size_t)bh * SEQ * HDIM;
    const size_t vbase  = (size_t)bh * HDIM * SEQ;

    // stage Q (128x64, swizzled) into KV[1] region (16KB)
    {
        bf16* Qst = &KV[1][0][0];
        #pragma unroll
        for (int i = 0; i < 4; ++i) {
            int c = tid + i * 256;           // 0..1023
            int row = c >> 3, ch = c & 7;
            int gch = ch ^ (row & 7);
            gload_lds16(Q + qkbase + (size_t)(q0 + row) * HDIM + gch * 8, &Qst[row * 64 + ch * 8]);
        }
    }
    // stage K/V tile 0 into buf 0 (disjoint region -> can issue now)
    auto stageKV = [&](int it, int buf) {
        #pragma unroll
        for (int i = 0; i < 2; ++i) {
            int c = tid + i * 256;           // 0..511
            int row = c >> 3, ch = c & 7;
            int gch = ch ^ (row & 7);
            gload_lds16(Kd + qkbase + (size_t)(it * 64 + row) * HDIM + gch * 8,
                        &KV[buf][0][row * 64 + ch * 8]);
            gload_lds16(Vt + vbase + (size_t)row * SEQ + it * 64 + gch * 8,
                        &KV[buf][1][row * 64 + ch * 8]);
        }
    };
    stageKV(0, 0);
    __syncthreads();   // Q + tile0 staged

    // Q fragments -> registers (16 VGPRs), then free the Q area
    bf16x8_t qf[2][2];
    {
        const bf16* Qst = &KV[1][0][0];
        #pragma unroll
        for (int q16 = 0; q16 < 2; ++q16) {
            int row = wq + q16 * 16 + lr;
            #pragma unroll
            for (int ks = 0; ks < 2; ++ks) {
                int ch = (ks * 4 + quad) ^ (row & 7);
                qf[q16][ks] = *reinterpret_cast<const bf16x8_t*>(&Qst[row * 64 + ch * 8]);
            }
        }
    }
    __syncthreads();   // all waves read Q; KV[1] reusable as buf 1

    f32x4_t oacc[2][4] = {};
    float rs[2] = {0.f, 0.f};

    for (int it = 0; it < SEQ / 64; ++it) {
        const int buf = it & 1;
        if (it + 1 < SEQ / 64) stageKV(it + 1, buf ^ 1);

        const bf16* Ks = &KV[buf][0][0];
        const bf16* Vs = &KV[buf][1][0];

        // S^T: A = K rows (M=key), B = Q rows (N=query)
        f32x4_t sacc[4][2] = {};
        #pragma unroll
        for (int ks = 0; ks < 2; ++ks) {
            bf16x8_t af[4];
            #pragma unroll
            for (int kt = 0; kt < 4; ++kt) {
                int row = kt * 16 + lr;
                int ch = (ks * 4 + quad) ^ (row & 7);
                af[kt] = *reinterpret_cast<const bf16x8_t*>(&Ks[row * 64 + ch * 8]);
            }
            #pragma unroll
            for (int kt = 0; kt < 4; ++kt)
                #pragma unroll
                for (int q16 = 0; q16 < 2; ++q16)
                    sacc[kt][q16] = __builtin_amdgcn_mfma_f32_16x16x32_bf16(
                        af[kt], qf[q16][ks], sacc[kt][q16], 0, 0, 0);
        }

        // p = exp(s/8); per-lane partial row sums; pack 4 consecutive keys -> b64 write
        #pragma unroll
        for (int kt = 0; kt < 4; ++kt) {
            #pragma unroll
            for (int q16 = 0; q16 < 2; ++q16) {
                bf16x4_t pk;
                float s0 = 0.f;
                #pragma unroll
                for (int r = 0; r < 4; ++r) {
                    float p = __expf(sacc[kt][q16][r] * 0.125f);
                    s0 += p;
                    pk[r] = (bf16)p;
                }
                rs[q16] += s0;
                *reinterpret_cast<bf16x4_t*>(&Ps[w][(q16 * 16 + lr) * PSTR + kt * 16 + quad * 4]) = pk;
            }
        }
        // no barrier: Ps is wave-private (compiler inserts lgkmcnt wait)

        // O += P * V
        #pragma unroll
        for (int ks = 0; ks < 2; ++ks) {
            bf16x8_t ap[2], bv[4];
            #pragma unroll
            for (int q16 = 0; q16 < 2; ++q16)
                ap[q16] = *reinterpret_cast<const bf16x8_t*>(
                    &Ps[w][(q16 * 16 + lr) * PSTR + ks * 32 + quad * 8]);
            #pragma unroll
            for (int dt = 0; dt < 4; ++dt) {
                int row = dt * 16 + lr;
                int ch = (ks * 4 + quad) ^ (row & 7);
                bv[dt] = *reinterpret_cast<const bf16x8_t*>(&Vs[row * 64 + ch * 8]);
            }
            #pragma unroll
            for (int q16 = 0; q16 < 2; ++q16)
                #pragma unroll
                for (int dt = 0; dt < 4; ++dt)
                    oacc[q16][dt] = __builtin_amdgcn_mfma_f32_16x16x32_bf16(
                        ap[q16], bv[dt], oacc[q16][dt], 0, 0, 0);
        }
        __syncthreads();   // one barrier per iter: protects buf for it+2 staging
    }

    // full row sums: reduce across quads (query lives at col=lr, all quads partial)
    #pragma unroll
    for (int q16 = 0; q16 < 2; ++q16) {
        rs[q16] += __shfl_xor(rs[q16], 16);
        rs[q16] += __shfl_xor(rs[q16], 32);
    }

    // normalize + store; O C-layout: row(query)=quad*4+r, col(d)=dt*16+lr
    #pragma unroll
    for (int q16 = 0; q16 < 2; ++q16) {
        float inv[4];
        #pragma unroll
        for (int r = 0; r < 4; ++r)
            inv[r] = 1.0f / __shfl(rs[q16], quad * 4 + r);
        #pragma unroll
        for (int dt = 0; dt < 4; ++dt) {
            #pragma unroll
            for (int r = 0; r < 4; ++r) {
                int q = q0 + wq + q16 * 16 + quad * 4 + r;
                Ab[((size_t)b * SEQ + q) * DIM + h * HDIM + dt * 16 + lr] =
                    (bf16)(oacc[q16][dt][r] * inv[r]);
            }
        }
    }
}

extern "C" void kernel_launch(void* const* d_in, const int* in_sizes, int n_in,
                              void* d_out, int out_size, void* d_ws, size_t ws_size,
                              hipStream_t stream) {
    (void)in_sizes; (void)n_in; (void)out_size; (void)ws_size;
    const float* x  = (const float*)d_in[0];
    const float* Wq = (const float*)d_in[1];
    const float* Wk = (const float*)d_in[2];
    const float* Wv = (const float*)d_in[3];
    const float* Wp = (const float*)d_in[4];
    const float* bp = (const float*)d_in[5];
    float* out = (float*)d_out;

    char* ws = (char*)d_ws;
    size_t off = 0;
    auto alloc = [&](size_t bytes) {
        void* p = ws + off;
        off += (bytes + 255) & ~(size_t)255;
        return p;
    };
    const size_t big = (size_t)MROWS * DIM * sizeof(bf16);
    const size_t wsz = (size_t)DIM * DIM * sizeof(bf16);
    bf16* Xb  = (bf16*)alloc(big);
    bf16* Qb  = (bf16*)alloc(big);
    bf16* Kb  = (bf16*)alloc(big);
    bf16* Vtb = (bf16*)alloc(big);
    bf16* Wqb = (bf16*)alloc(wsz);
    bf16* Wkb = (bf16*)alloc(wsz);
    bf16* Wvb = (bf16*)alloc(wsz);
    bf16* Wpb = (bf16*)alloc(wsz);
    bf16* Ab  = Xb;   // Xb dead after qkv_gemm

    const int x4 = MROWS * DIM / 4;
    cast_bf16_kernel<<<(x4 + 255) / 256, 256, 0, stream>>>(x, Xb, x4);
    const int w4 = DIM * DIM / 4;
    cast_bf16_kernel<<<(w4 + 255) / 256, 256, 0, stream>>>(Wq, Wqb, w4);
    cast_bf16_kernel<<<(w4 + 255) / 256, 256, 0, stream>>>(Wk, Wkb, w4);
    cast_bf16_kernel<<<(w4 + 255) / 256, 256, 0, stream>>>(Wv, Wvb, w4);
    cast_bf16_kernel<<<(w4 + 255) / 256, 256, 0, stream>>>(Wp, Wpb, w4);

    qkv_gemm<<<dim3(DIM / 128, MROWS / 128, 3), 256, 0, stream>>>(Xb, Wqb, Wkb, Wvb, Qb, Kb, Vtb);

    attn_kernel<<<dim3(SEQ / 128, BATCH * HEADS), 256, 0, stream>>>(Qb, Kb, Vtb, Ab);

    out_gemm<<<dim3(DIM / 128, MROWS / 128), 256, 0, stream>>>(Ab, Wpb, bp, out);
}

// Round 4
// 252.334 us; speedup vs baseline: 1.4419x; 1.0195x over previous
//
#include <hip/hip_runtime.h>
#include <cstdint>

#define DIM   768
#define HEADS 12
#define HDIM  64
#define BATCH 4
#define SEQ   2048
#define MROWS (BATCH*SEQ)   // 8192

typedef __bf16 bf16;
typedef __bf16 bf16x4_t __attribute__((ext_vector_type(4)));
typedef __bf16 bf16x8_t __attribute__((ext_vector_type(8)));
typedef float  f32x4_t  __attribute__((ext_vector_type(4)));
typedef short  short4_t __attribute__((ext_vector_type(4)));

// K=16 bf16 MFMA: A/B = 4 bf16 (2 VGPR), C/D = 4 f32. Name differs across ROCm vers.
__device__ __forceinline__ f32x4_t mfma16x16x16bf16(bf16x4_t a, bf16x4_t b, f32x4_t c) {
#if __has_builtin(__builtin_amdgcn_mfma_f32_16x16x16_bf16)
    return __builtin_amdgcn_mfma_f32_16x16x16_bf16(a, b, c, 0, 0, 0);
#elif __has_builtin(__builtin_amdgcn_mfma_f32_16x16x16bf16_1k)
    union U { bf16x4_t h; short4_t s; };
    U ua, ub; ua.h = a; ub.h = b;
    return __builtin_amdgcn_mfma_f32_16x16x16bf16_1k(ua.s, ub.s, c, 0, 0, 0);
#else
    asm("v_mfma_f32_16x16x16_bf16 %0, %1, %2, %0" : "+v"(c) : "v"(a), "v"(b));
    return c;
#endif
}

// ---------------- fp32 -> bf16 casts ----------------
__global__ void cast_bf16_kernel(const float* __restrict__ src, bf16* __restrict__ dst, int n4) {
    int i = blockIdx.x * blockDim.x + threadIdx.x;
    if (i >= n4) return;
    const float4 v = reinterpret_cast<const float4*>(src)[i];
    bf16x4_t o;
    o[0] = (bf16)v.x; o[1] = (bf16)v.y; o[2] = (bf16)v.z; o[3] = (bf16)v.w;
    reinterpret_cast<bf16x4_t*>(dst)[i] = o;
}

__global__ void cast_w4_kernel(const float* __restrict__ s0, const float* __restrict__ s1,
                               const float* __restrict__ s2, const float* __restrict__ s3,
                               bf16* __restrict__ d0, bf16* __restrict__ d1,
                               bf16* __restrict__ d2, bf16* __restrict__ d3, int n4) {
    int i = blockIdx.x * blockDim.x + threadIdx.x;
    if (i >= n4) return;
    int y = blockIdx.y;
    const float* src = (y == 0) ? s0 : (y == 1) ? s1 : (y == 2) ? s2 : s3;
    bf16* dst        = (y == 0) ? d0 : (y == 1) ? d1 : (y == 2) ? d2 : d3;
    const float4 v = reinterpret_cast<const float4*>(src)[i];
    bf16x4_t o;
    o[0] = (bf16)v.x; o[1] = (bf16)v.y; o[2] = (bf16)v.z; o[3] = (bf16)v.w;
    reinterpret_cast<bf16x4_t*>(dst)[i] = o;
}

// async global->LDS, 16B per lane. LDS dest is wave-uniform base + lane*16.
__device__ __forceinline__ void gload_lds16(const bf16* g, bf16* l) {
    __builtin_amdgcn_global_load_lds((const __attribute__((address_space(1))) void*)g,
                                     (__attribute__((address_space(3))) void*)l, 16, 0, 0);
}

// ---------------- QKV projection GEMM ----------------
__global__ __launch_bounds__(256, 2) void qkv_gemm(
        const bf16* __restrict__ X,
        const bf16* __restrict__ Wq, const bf16* __restrict__ Wk, const bf16* __restrict__ Wv,
        bf16* __restrict__ Q, bf16* __restrict__ Kd, bf16* __restrict__ Vt)
{
    __shared__ bf16 As[128*32];
    __shared__ bf16 Bs[128*32];
    const int tid  = threadIdx.x;
    const int z    = blockIdx.z;
    const bf16* W  = (z == 0) ? Wq : (z == 1 ? Wk : Wv);
    const int n0   = blockIdx.x * 128;
    const int m0   = blockIdx.y * 128;
    const int lane = tid & 63;
    const int w    = tid >> 6;
    const int wm   = (w & 1) * 64, wn = (w >> 1) * 64;
    const int lr   = lane & 15, quad = lane >> 4;

    f32x4_t acc[4][4] = {};

    for (int kk = 0; kk < DIM; kk += 32) {
        #pragma unroll
        for (int i = 0; i < 2; ++i) {
            int c = tid + i * 256;
            int row = c >> 2, ko = (c & 3) * 8;
            gload_lds16(X + (size_t)(m0 + row) * DIM + kk + ko, &As[row * 32 + ko]);
            gload_lds16(W + (size_t)(n0 + row) * DIM + kk + ko, &Bs[row * 32 + ko]);
        }
        __syncthreads();
        bf16x8_t af[4], bfr[4];
        #pragma unroll
        for (int i = 0; i < 4; ++i)
            af[i] = *reinterpret_cast<const bf16x8_t*>(&As[(wm + i * 16 + lr) * 32 + quad * 8]);
        #pragma unroll
        for (int j = 0; j < 4; ++j)
            bfr[j] = *reinterpret_cast<const bf16x8_t*>(&Bs[(wn + j * 16 + lr) * 32 + quad * 8]);
        #pragma unroll
        for (int i = 0; i < 4; ++i)
            #pragma unroll
            for (int j = 0; j < 4; ++j)
                acc[i][j] = __builtin_amdgcn_mfma_f32_16x16x32_bf16(af[i], bfr[j], acc[i][j], 0, 0, 0);
        __syncthreads();
    }

    #pragma unroll
    for (int i = 0; i < 4; ++i) {
        int mbase = m0 + wm + i * 16 + quad * 4;
        #pragma unroll
        for (int j = 0; j < 4; ++j) {
            int n = n0 + wn + j * 16 + lr;
            int h = n >> 6, d = n & 63;
            #pragma unroll
            for (int r = 0; r < 4; ++r) {
                int m = mbase + r;
                int b = m >> 11, row = m & 2047;
                bf16 v = (bf16)acc[i][j][r];
                if (z < 2) {
                    bf16* dst = (z == 0) ? Q : Kd;
                    dst[(((size_t)b * HEADS + h) * SEQ + row) * HDIM + d] = v;
                } else {
                    Vt[(((size_t)b * HEADS + h) * HDIM + d) * SEQ + row] = v;
                }
            }
        }
    }
}

// ---------------- output projection GEMM (+bias, fp32 out) ----------------
__global__ __launch_bounds__(256, 2) void out_gemm(
        const bf16* __restrict__ A,
        const bf16* __restrict__ W,
        const float* __restrict__ bias,
        float* __restrict__ out)
{
    __shared__ bf16 As[128*32];
    __shared__ bf16 Bs[128*32];
    const int tid  = threadIdx.x;
    const int n0   = blockIdx.x * 128;
    const int m0   = blockIdx.y * 128;
    const int lane = tid & 63;
    const int w    = tid >> 6;
    const int wm   = (w & 1) * 64, wn = (w >> 1) * 64;
    const int lr   = lane & 15, quad = lane >> 4;

    f32x4_t acc[4][4] = {};

    for (int kk = 0; kk < DIM; kk += 32) {
        #pragma unroll
        for (int i = 0; i < 2; ++i) {
            int c = tid + i * 256;
            int row = c >> 2, ko = (c & 3) * 8;
            gload_lds16(A + (size_t)(m0 + row) * DIM + kk + ko, &As[row * 32 + ko]);
            gload_lds16(W + (size_t)(n0 + row) * DIM + kk + ko, &Bs[row * 32 + ko]);
        }
        __syncthreads();
        bf16x8_t af[4], bfr[4];
        #pragma unroll
        for (int i = 0; i < 4; ++i)
            af[i] = *reinterpret_cast<const bf16x8_t*>(&As[(wm + i * 16 + lr) * 32 + quad * 8]);
        #pragma unroll
        for (int j = 0; j < 4; ++j)
            bfr[j] = *reinterpret_cast<const bf16x8_t*>(&Bs[(wn + j * 16 + lr) * 32 + quad * 8]);
        #pragma unroll
        for (int i = 0; i < 4; ++i)
            #pragma unroll
            for (int j = 0; j < 4; ++j)
                acc[i][j] = __builtin_amdgcn_mfma_f32_16x16x32_bf16(af[i], bfr[j], acc[i][j], 0, 0, 0);
        __syncthreads();
    }

    #pragma unroll
    for (int i = 0; i < 4; ++i) {
        int mbase = m0 + wm + i * 16 + quad * 4;
        #pragma unroll
        for (int j = 0; j < 4; ++j) {
            int n = n0 + wn + j * 16 + lr;
            float bv = bias[n];
            #pragma unroll
            for (int r = 0; r < 4; ++r) {
                int m = mbase + r;
                out[(size_t)m * DIM + n] = acc[i][j][r] + bv;
            }
        }
    }
}

// ---------------- flash attention v3 ----------------
// Q-tile 128 (wave owns 32 queries, Q frags in regs), K-tile 64 double-buffered.
// S computed transposed (key=M, query=N); its C-layout (lane: query=lr, keys
// 16kt+quad*4+r) IS the A-operand layout of the K=16 MFMA, so P feeds PV
// straight from registers: no LDS round-trip, no cross-lane. LDS = 32 KB.
__global__ __launch_bounds__(256, 4) void attn_kernel(
        const bf16* __restrict__ Q, const bf16* __restrict__ Kd,
        const bf16* __restrict__ Vt, bf16* __restrict__ Ab)
{
    __shared__ __align__(16) bf16 KV[2][2][64*64];   // [buf][K|V][row*64] swizzled

    const int tid  = threadIdx.x;
    const int bh   = blockIdx.y;
    const int b    = bh / HEADS, h = bh % HEADS;
    const int q0   = blockIdx.x * 128;
    const int lane = tid & 63, w = tid >> 6;
    const int lr   = lane & 15, quad = lane >> 4;
    const int wq   = w * 32;

    const size_t qkbase = (size_t)bh * SEQ * HDIM;
    const size_t vbase  = (size_t)bh * HDIM * SEQ;

    // stage Q (128x64, swizzled) into KV[1] (16 KB)
    {
        bf16* Qst = &KV[1][0][0];
        #pragma unroll
        for (int i = 0; i < 4; ++i) {
            int c = tid + i * 256;
            int row = c >> 3, ch = c & 7;
            int gch = ch ^ (row & 7);
            gload_lds16(Q + qkbase + (size_t)(q0 + row) * HDIM + gch * 8, &Qst[row * 64 + ch * 8]);
        }
    }
    auto stageKV = [&](int it, int buf) {
        #pragma unroll
        for (int i = 0; i < 2; ++i) {
            int c = tid + i * 256;
            int row = c >> 3, ch = c & 7;
            int gch = ch ^ (row & 7);
            gload_lds16(Kd + qkbase + (size_t)(it * 64 + row) * HDIM + gch * 8,
                        &KV[buf][0][row * 64 + ch * 8]);
            gload_lds16(Vt + vbase + (size_t)row * SEQ + it * 64 + gch * 8,
                        &KV[buf][1][row * 64 + ch * 8]);
        }
    };
    stageKV(0, 0);
    __syncthreads();   // Q + tile0 staged

    // Q B-operand fragments -> registers (16 VGPRs)
    bf16x8_t qf[2][2];
    {
        const bf16* Qst = &KV[1][0][0];
        #pragma unroll
        for (int q16 = 0; q16 < 2; ++q16) {
            int row = wq + q16 * 16 + lr;
            #pragma unroll
            for (int ks = 0; ks < 2; ++ks) {
                int ch = (ks * 4 + quad) ^ (row & 7);
                qf[q16][ks] = *reinterpret_cast<const bf16x8_t*>(&Qst[row * 64 + ch * 8]);
            }
        }
    }
    __syncthreads();   // all waves read Q; KV[1] becomes buf 1

    f32x4_t oacc[2][4] = {};
    float rs[2] = {0.f, 0.f};
    const float c_scale = 0.18033688011112042f;   // (1/8) * log2(e)

    for (int it = 0; it < SEQ / 64; ++it) {
        const int buf = it & 1;
        if (it + 1 < SEQ / 64) stageKV(it + 1, buf ^ 1);

        const bf16* Ks = &KV[buf][0][0];
        const bf16* Vs = &KV[buf][1][0];

        // S^T: A = K rows (M=key), B = Q rows (N=query), 16x16x32
        f32x4_t sacc[4][2] = {};
        #pragma unroll
        for (int ks = 0; ks < 2; ++ks) {
            bf16x8_t af[4];
            #pragma unroll
            for (int kt = 0; kt < 4; ++kt) {
                int row = kt * 16 + lr;
                int ch = (ks * 4 + quad) ^ (row & 7);
                af[kt] = *reinterpret_cast<const bf16x8_t*>(&Ks[row * 64 + ch * 8]);
            }
            #pragma unroll
            for (int kt = 0; kt < 4; ++kt)
                #pragma unroll
                for (int q16 = 0; q16 < 2; ++q16)
                    sacc[kt][q16] = __builtin_amdgcn_mfma_f32_16x16x32_bf16(
                        af[kt], qf[q16][ks], sacc[kt][q16], 0, 0, 0);
        }

        // p = exp2(s*scale); pk (keys 16kt+quad*4+r at query col lr) is already
        // the K=16 A-operand frag -> PV straight from registers.
        #pragma unroll
        for (int kt = 0; kt < 4; ++kt) {
            bf16x4_t bv[4];
            #pragma unroll
            for (int dt = 0; dt < 4; ++dt) {
                int row = dt * 16 + lr;
                int ch = (2 * kt + (quad >> 1)) ^ (row & 7);
                bv[dt] = *reinterpret_cast<const bf16x4_t*>(&Vs[row * 64 + ch * 8 + (quad & 1) * 4]);
            }
            #pragma unroll
            for (int q16 = 0; q16 < 2; ++q16) {
                bf16x4_t pk;
                float s0 = 0.f;
                #pragma unroll
                for (int r = 0; r < 4; ++r) {
                    float p = __builtin_amdgcn_exp2f(sacc[kt][q16][r] * c_scale);
                    s0 += p;
                    pk[r] = (bf16)p;
                }
                rs[q16] += s0;
                #pragma unroll
                for (int dt = 0; dt < 4; ++dt)
                    oacc[q16][dt] = mfma16x16x16bf16(pk, bv[dt], oacc[q16][dt]);
            }
        }
        __syncthreads();   // protects buf for it+2 staging
    }

    // full row sums: reduce across quads/halves (query col = lr)
    #pragma unroll
    for (int q16 = 0; q16 < 2; ++q16) {
        rs[q16] += __shfl_xor(rs[q16], 16);
        rs[q16] += __shfl_xor(rs[q16], 32);
    }

    // normalize + store; O C-layout: row(query)=quad*4+r, col(d)=dt*16+lr
    #pragma unroll
    for (int q16 = 0; q16 < 2; ++q16) {
        float inv[4];
        #pragma unroll
        for (int r = 0; r < 4; ++r)
            inv[r] = 1.0f / __shfl(rs[q16], quad * 4 + r);
        #pragma unroll
        for (int dt = 0; dt < 4; ++dt) {
            #pragma unroll
            for (int r = 0; r < 4; ++r) {
                int q = q0 + wq + q16 * 16 + quad * 4 + r;
                Ab[((size_t)b * SEQ + q) * DIM + h * HDIM + dt * 16 + lr] =
                    (bf16)(oacc[q16][dt][r] * inv[r]);
            }
        }
    }
}

extern "C" void kernel_launch(void* const* d_in, const int* in_sizes, int n_in,
                              void* d_out, int out_size, void* d_ws, size_t ws_size,
                              hipStream_t stream) {
    (void)in_sizes; (void)n_in; (void)out_size; (void)ws_size;
    const float* x  = (const float*)d_in[0];
    const float* Wq = (const float*)d_in[1];
    const float* Wk = (const float*)d_in[2];
    const float* Wv = (const float*)d_in[3];
    const float* Wp = (const float*)d_in[4];
    const float* bp = (const float*)d_in[5];
    float* out = (float*)d_out;

    char* ws = (char*)d_ws;
    size_t off = 0;
    auto alloc = [&](size_t bytes) {
        void* p = ws + off;
        off += (bytes + 255) & ~(size_t)255;
        return p;
    };
    const size_t big = (size_t)MROWS * DIM * sizeof(bf16);
    const size_t wsz = (size_t)DIM * DIM * sizeof(bf16);
    bf16* Xb  = (bf16*)alloc(big);
    bf16* Qb  = (bf16*)alloc(big);
    bf16* Kb  = (bf16*)alloc(big);
    bf16* Vtb = (bf16*)alloc(big);
    bf16* Wqb = (bf16*)alloc(wsz);
    bf16* Wkb = (bf16*)alloc(wsz);
    bf16* Wvb = (bf16*)alloc(wsz);
    bf16* Wpb = (bf16*)alloc(wsz);
    bf16* Ab  = Xb;   // Xb dead after qkv_gemm

    const int x4 = MROWS * DIM / 4;
    cast_bf16_kernel<<<(x4 + 255) / 256, 256, 0, stream>>>(x, Xb, x4);
    const int w4 = DIM * DIM / 4;
    cast_w4_kernel<<<dim3((w4 + 255) / 256, 4), 256, 0, stream>>>(
        Wq, Wk, Wv, Wp, Wqb, Wkb, Wvb, Wpb, w4);

    qkv_gemm<<<dim3(DIM / 128, MROWS / 128, 3), 256, 0, stream>>>(Xb, Wqb, Wkb, Wvb, Qb, Kb, Vtb);

    attn_kernel<<<dim3(SEQ / 128, BATCH * HEADS), 256, 0, stream>>>(Qb, Kb, Vtb, Ab);

    out_gemm<<<dim3(DIM / 128, MROWS / 128), 256, 0, stream>>>(Ab, Wpb, bp, out);
}

// Round 5
// 234.128 us; speedup vs baseline: 1.5540x; 1.0778x over previous
//
#include <hip/hip_runtime.h>
#include <cstdint>

#define DIM   768
#define HEADS 12
#define HDIM  64
#define BATCH 4
#define SEQ   2048
#define MROWS (BATCH*SEQ)   // 8192

typedef __bf16 bf16;
typedef __bf16 bf16x4_t __attribute__((ext_vector_type(4)));
typedef __bf16 bf16x8_t __attribute__((ext_vector_type(8)));
typedef float  f32x4_t  __attribute__((ext_vector_type(4)));
typedef short  short4_t __attribute__((ext_vector_type(4)));

// K=16 bf16 MFMA: A/B = 4 bf16 (2 VGPR), C/D = 4 f32.
__device__ __forceinline__ f32x4_t mfma16x16x16bf16(bf16x4_t a, bf16x4_t b, f32x4_t c) {
#if __has_builtin(__builtin_amdgcn_mfma_f32_16x16x16_bf16)
    return __builtin_amdgcn_mfma_f32_16x16x16_bf16(a, b, c, 0, 0, 0);
#elif __has_builtin(__builtin_amdgcn_mfma_f32_16x16x16bf16_1k)
    union U { bf16x4_t h; short4_t s; };
    U ua, ub; ua.h = a; ub.h = b;
    return __builtin_amdgcn_mfma_f32_16x16x16bf16_1k(ua.s, ub.s, c, 0, 0, 0);
#else
    asm("v_mfma_f32_16x16x16_bf16 %0, %1, %2, %0" : "+v"(c) : "v"(a), "v"(b));
    return c;
#endif
}

// ---------------- fp32 -> bf16 casts ----------------
__global__ void cast_bf16_kernel(const float* __restrict__ src, bf16* __restrict__ dst, int n4) {
    int i = blockIdx.x * blockDim.x + threadIdx.x;
    if (i >= n4) return;
    const float4 v = reinterpret_cast<const float4*>(src)[i];
    bf16x4_t o;
    o[0] = (bf16)v.x; o[1] = (bf16)v.y; o[2] = (bf16)v.z; o[3] = (bf16)v.w;
    reinterpret_cast<bf16x4_t*>(dst)[i] = o;
}

__global__ void cast_w4_kernel(const float* __restrict__ s0, const float* __restrict__ s1,
                               const float* __restrict__ s2, const float* __restrict__ s3,
                               bf16* __restrict__ d0, bf16* __restrict__ d1,
                               bf16* __restrict__ d2, bf16* __restrict__ d3, int n4) {
    int i = blockIdx.x * blockDim.x + threadIdx.x;
    if (i >= n4) return;
    int y = blockIdx.y;
    const float* src = (y == 0) ? s0 : (y == 1) ? s1 : (y == 2) ? s2 : s3;
    bf16* dst        = (y == 0) ? d0 : (y == 1) ? d1 : (y == 2) ? d2 : d3;
    const float4 v = reinterpret_cast<const float4*>(src)[i];
    bf16x4_t o;
    o[0] = (bf16)v.x; o[1] = (bf16)v.y; o[2] = (bf16)v.z; o[3] = (bf16)v.w;
    reinterpret_cast<bf16x4_t*>(dst)[i] = o;
}

// async global->LDS, 16B per lane. LDS dest is wave-uniform base + lane*16.
__device__ __forceinline__ void gload_lds16(const bf16* g, bf16* l) {
    __builtin_amdgcn_global_load_lds((const __attribute__((address_space(1))) void*)g,
                                     (__attribute__((address_space(3))) void*)l, 16, 0, 0);
}

// ---------------- Q/K projection GEMM ----------------
// z=0 -> Q [B,H,N,64] (pre-scaled by log2(e)/8), z=1 -> K [B,H,N,64]
__global__ __launch_bounds__(256, 2) void qkv_gemm(
        const bf16* __restrict__ X,
        const bf16* __restrict__ Wq, const bf16* __restrict__ Wk,
        bf16* __restrict__ Q, bf16* __restrict__ Kd)
{
    __shared__ bf16 As[128*32];
    __shared__ bf16 Bs[128*32];
    const int tid  = threadIdx.x;
    const int z    = blockIdx.z;
    const bf16* W  = (z == 0) ? Wq : Wk;
    const int n0   = blockIdx.x * 128;
    const int m0   = blockIdx.y * 128;
    const int lane = tid & 63;
    const int w    = tid >> 6;
    const int wm   = (w & 1) * 64, wn = (w >> 1) * 64;
    const int lr   = lane & 15, quad = lane >> 4;

    f32x4_t acc[4][4] = {};

    for (int kk = 0; kk < DIM; kk += 32) {
        #pragma unroll
        for (int i = 0; i < 2; ++i) {
            int c = tid + i * 256;
            int row = c >> 2, ko = (c & 3) * 8;
            gload_lds16(X + (size_t)(m0 + row) * DIM + kk + ko, &As[row * 32 + ko]);
            gload_lds16(W + (size_t)(n0 + row) * DIM + kk + ko, &Bs[row * 32 + ko]);
        }
        __syncthreads();
        bf16x8_t af[4], bfr[4];
        #pragma unroll
        for (int i = 0; i < 4; ++i)
            af[i] = *reinterpret_cast<const bf16x8_t*>(&As[(wm + i * 16 + lr) * 32 + quad * 8]);
        #pragma unroll
        for (int j = 0; j < 4; ++j)
            bfr[j] = *reinterpret_cast<const bf16x8_t*>(&Bs[(wn + j * 16 + lr) * 32 + quad * 8]);
        #pragma unroll
        for (int i = 0; i < 4; ++i)
            #pragma unroll
            for (int j = 0; j < 4; ++j)
                acc[i][j] = __builtin_amdgcn_mfma_f32_16x16x32_bf16(af[i], bfr[j], acc[i][j], 0, 0, 0);
        __syncthreads();
    }

    const float sc = (z == 0) ? 0.18033688011112042f : 1.0f;  // log2(e)/8 folded into Q
    bf16* dst = (z == 0) ? Q : Kd;
    #pragma unroll
    for (int i = 0; i < 4; ++i) {
        int mbase = m0 + wm + i * 16 + quad * 4;
        #pragma unroll
        for (int j = 0; j < 4; ++j) {
            int n = n0 + wn + j * 16 + lr;
            int h = n >> 6, d = n & 63;
            #pragma unroll
            for (int r = 0; r < 4; ++r) {
                int m = mbase + r;
                int b = m >> 11, row = m & 2047;
                dst[(((size_t)b * HEADS + h) * SEQ + row) * HDIM + d] = (bf16)(acc[i][j][r] * sc);
            }
        }
    }
}

// ---------------- V^T GEMM: Vt[768][8192] = Wv · X^T (row-major, coalesced) ----------------
__global__ __launch_bounds__(256, 2) void vt_gemm(
        const bf16* __restrict__ Wv,   // [768,768] "A" (M rows = d_full)
        const bf16* __restrict__ X,    // [8192,768] "B" (N rows = sample)
        bf16* __restrict__ Vt)         // [768, 8192]
{
    __shared__ bf16 As[128*32];
    __shared__ bf16 Bs[128*32];
    const int tid  = threadIdx.x;
    const int n0   = blockIdx.x * 128;     // sample
    const int m0   = blockIdx.y * 128;     // d_full
    const int lane = tid & 63;
    const int w    = tid >> 6;
    const int wm   = (w & 1) * 64, wn = (w >> 1) * 64;
    const int lr   = lane & 15, quad = lane >> 4;

    f32x4_t acc[4][4] = {};

    for (int kk = 0; kk < DIM; kk += 32) {
        #pragma unroll
        for (int i = 0; i < 2; ++i) {
            int c = tid + i * 256;
            int row = c >> 2, ko = (c & 3) * 8;
            gload_lds16(Wv + (size_t)(m0 + row) * DIM + kk + ko, &As[row * 32 + ko]);
            gload_lds16(X  + (size_t)(n0 + row) * DIM + kk + ko, &Bs[row * 32 + ko]);
        }
        __syncthreads();
        bf16x8_t af[4], bfr[4];
        #pragma unroll
        for (int i = 0; i < 4; ++i)
            af[i] = *reinterpret_cast<const bf16x8_t*>(&As[(wm + i * 16 + lr) * 32 + quad * 8]);
        #pragma unroll
        for (int j = 0; j < 4; ++j)
            bfr[j] = *reinterpret_cast<const bf16x8_t*>(&Bs[(wn + j * 16 + lr) * 32 + quad * 8]);
        #pragma unroll
        for (int i = 0; i < 4; ++i)
            #pragma unroll
            for (int j = 0; j < 4; ++j)
                acc[i][j] = __builtin_amdgcn_mfma_f32_16x16x32_bf16(af[i], bfr[j], acc[i][j], 0, 0, 0);
        __syncthreads();
    }

    #pragma unroll
    for (int i = 0; i < 4; ++i) {
        int mbase = m0 + wm + i * 16 + quad * 4;
        #pragma unroll
        for (int j = 0; j < 4; ++j) {
            int n = n0 + wn + j * 16 + lr;
            #pragma unroll
            for (int r = 0; r < 4; ++r)
                Vt[(size_t)(mbase + r) * MROWS + n] = (bf16)acc[i][j][r];
        }
    }
}

// ---------------- output projection GEMM (+bias, fp32 out) ----------------
__global__ __launch_bounds__(256, 2) void out_gemm(
        const bf16* __restrict__ A,
        const bf16* __restrict__ W,
        const float* __restrict__ bias,
        float* __restrict__ out)
{
    __shared__ bf16 As[128*32];
    __shared__ bf16 Bs[128*32];
    const int tid  = threadIdx.x;
    const int n0   = blockIdx.x * 128;
    const int m0   = blockIdx.y * 128;
    const int lane = tid & 63;
    const int w    = tid >> 6;
    const int wm   = (w & 1) * 64, wn = (w >> 1) * 64;
    const int lr   = lane & 15, quad = lane >> 4;

    f32x4_t acc[4][4] = {};

    for (int kk = 0; kk < DIM; kk += 32) {
        #pragma unroll
        for (int i = 0; i < 2; ++i) {
            int c = tid + i * 256;
            int row = c >> 2, ko = (c & 3) * 8;
            gload_lds16(A + (size_t)(m0 + row) * DIM + kk + ko, &As[row * 32 + ko]);
            gload_lds16(W + (size_t)(n0 + row) * DIM + kk + ko, &Bs[row * 32 + ko]);
        }
        __syncthreads();
        bf16x8_t af[4], bfr[4];
        #pragma unroll
        for (int i = 0; i < 4; ++i)
            af[i] = *reinterpret_cast<const bf16x8_t*>(&As[(wm + i * 16 + lr) * 32 + quad * 8]);
        #pragma unroll
        for (int j = 0; j < 4; ++j)
            bfr[j] = *reinterpret_cast<const bf16x8_t*>(&Bs[(wn + j * 16 + lr) * 32 + quad * 8]);
        #pragma unroll
        for (int i = 0; i < 4; ++i)
            #pragma unroll
            for (int j = 0; j < 4; ++j)
                acc[i][j] = __builtin_amdgcn_mfma_f32_16x16x32_bf16(af[i], bfr[j], acc[i][j], 0, 0, 0);
        __syncthreads();
    }

    #pragma unroll
    for (int i = 0; i < 4; ++i) {
        int mbase = m0 + wm + i * 16 + quad * 4;
        #pragma unroll
        for (int j = 0; j < 4; ++j) {
            int n = n0 + wn + j * 16 + lr;
            float bv = bias[n];
            #pragma unroll
            for (int r = 0; r < 4; ++r) {
                int m = mbase + r;
                out[(size_t)m * DIM + n] = acc[i][j][r] + bv;
            }
        }
    }
}

// ---------------- flash attention v4 ----------------
// Q pre-scaled by log2(e)/8 -> p = exp2(s) directly. Row sums via MFMA with an
// all-ones B fragment (lands in the same lane mapping as oacc -> no shuffles).
// V^T is [768][8192]: d-stride = MROWS.
__global__ __launch_bounds__(256, 4) void attn_kernel(
        const bf16* __restrict__ Q, const bf16* __restrict__ Kd,
        const bf16* __restrict__ Vt, bf16* __restrict__ Ab)
{
    __shared__ __align__(16) bf16 KV[2][2][64*64];   // [buf][K|V][row*64] swizzled

    const int tid  = threadIdx.x;
    const int bh   = blockIdx.y;
    const int b    = bh / HEADS, h = bh % HEADS;
    const int q0   = blockIdx.x * 128;
    const int lane = tid & 63, w = tid >> 6;
    const int lr   = lane & 15, quad = lane >> 4;
    const int wq   = w * 32;

    const size_t qkbase = (size_t)bh * SEQ * HDIM;
    const size_t vbase  = (size_t)h * HDIM * MROWS + (size_t)b * SEQ;

    // per-lane staging coords (loop-invariant)
    const int src_row = tid >> 3, src_ch = tid & 7;
    const int src_gch = src_ch ^ (src_row & 7);
    const int src_row2 = (tid + 256) >> 3, src_ch2 = tid & 7;   // c+256: row+32, same ch
    const int src_gch2 = src_ch2 ^ (src_row2 & 7);

    // stage Q (128x64, swizzled) into KV[1] (16 KB)
    {
        bf16* Qst = &KV[1][0][0];
        #pragma unroll
        for (int i = 0; i < 4; ++i) {
            int c = tid + i * 256;
            int row = c >> 3, ch = c & 7;
            int gch = ch ^ (row & 7);
            gload_lds16(Q + qkbase + (size_t)(q0 + row) * HDIM + gch * 8, &Qst[row * 64 + ch * 8]);
        }
    }

    // staging pointers, advanced by constant stride per tile
    const bf16* kp1 = Kd + qkbase + (size_t)src_row  * HDIM + src_gch  * 8;
    const bf16* kp2 = Kd + qkbase + (size_t)src_row2 * HDIM + src_gch2 * 8;
    const bf16* vp1 = Vt + vbase  + (size_t)src_row  * MROWS + src_gch  * 8;
    const bf16* vp2 = Vt + vbase  + (size_t)src_row2 * MROWS + src_gch2 * 8;
    bf16* kl1 = &KV[0][0][src_row  * 64 + src_ch  * 8];
    bf16* kl2 = &KV[0][0][src_row2 * 64 + src_ch2 * 8];
    bf16* vl1 = &KV[0][1][src_row  * 64 + src_ch  * 8];
    bf16* vl2 = &KV[0][1][src_row2 * 64 + src_ch2 * 8];
    const ptrdiff_t kstep = 64 * HDIM, vstep = 64;
    const ptrdiff_t lstep = 2 * 64 * 64;   // buf stride in elems

    // tile 0 -> buf 0
    gload_lds16(kp1, kl1); gload_lds16(kp2, kl2);
    gload_lds16(vp1, vl1); gload_lds16(vp2, vl2);
    __syncthreads();

    // Q B-operand fragments -> registers
    bf16x8_t qf[2][2];
    {
        const bf16* Qst = &KV[1][0][0];
        #pragma unroll
        for (int q16 = 0; q16 < 2; ++q16) {
            int row = wq + q16 * 16 + lr;
            #pragma unroll
            for (int ks = 0; ks < 2; ++ks) {
                int ch = (ks * 4 + quad) ^ (row & 7);
                qf[q16][ks] = *reinterpret_cast<const bf16x8_t*>(&Qst[row * 64 + ch * 8]);
            }
        }
    }
    __syncthreads();   // all waves read Q; KV[1] becomes buf 1

    f32x4_t oacc[2][4] = {};
    f32x4_t rsacc[2] = {};
    bf16x4_t ones4;
    ones4[0] = (bf16)1.0f; ones4[1] = (bf16)1.0f; ones4[2] = (bf16)1.0f; ones4[3] = (bf16)1.0f;

    for (int it = 0; it < SEQ / 64; ++it) {
        const int buf = it & 1;
        if (it + 1 < SEQ / 64) {
            const ptrdiff_t g = (ptrdiff_t)(it + 1);
            const ptrdiff_t l = (buf ^ 1) ? lstep : 0;
            gload_lds16(kp1 + g * kstep, kl1 + l); gload_lds16(kp2 + g * kstep, kl2 + l);
            gload_lds16(vp1 + g * vstep, vl1 + l); gload_lds16(vp2 + g * vstep, vl2 + l);
        }

        const bf16* Ks = &KV[buf][0][0];
        const bf16* Vs = &KV[buf][1][0];

        // S^T: A = K rows (M=key), B = Q rows (N=query), 16x16x32
        f32x4_t sacc[4][2] = {};
        #pragma unroll
        for (int ks = 0; ks < 2; ++ks) {
            bf16x8_t af[4];
            #pragma unroll
            for (int kt = 0; kt < 4; ++kt) {
                int row = kt * 16 + lr;
                int ch = (ks * 4 + quad) ^ (row & 7);
                af[kt] = *reinterpret_cast<const bf16x8_t*>(&Ks[row * 64 + ch * 8]);
            }
            #pragma unroll
            for (int kt = 0; kt < 4; ++kt)
                #pragma unroll
                for (int q16 = 0; q16 < 2; ++q16)
                    sacc[kt][q16] = __builtin_amdgcn_mfma_f32_16x16x32_bf16(
                        af[kt], qf[q16][ks], sacc[kt][q16], 0, 0, 0);
        }

        // p = exp2(s); pk is already the K=16 A-operand frag.
        #pragma unroll
        for (int kt = 0; kt < 4; ++kt) {
            bf16x4_t bv[4];
            #pragma unroll
            for (int dt = 0; dt < 4; ++dt) {
                int row = dt * 16 + lr;
                int ch = (2 * kt + (quad >> 1)) ^ (row & 7);
                bv[dt] = *reinterpret_cast<const bf16x4_t*>(&Vs[row * 64 + ch * 8 + (quad & 1) * 4]);
            }
            #pragma unroll
            for (int q16 = 0; q16 < 2; ++q16) {
                bf16x4_t pk;
                #pragma unroll
                for (int r = 0; r < 4; ++r)
                    pk[r] = (bf16)__builtin_amdgcn_exp2f(sacc[kt][q16][r]);
                rsacc[q16] = mfma16x16x16bf16(pk, ones4, rsacc[q16]);   // row sums
                #pragma unroll
                for (int dt = 0; dt < 4; ++dt)
                    oacc[q16][dt] = mfma16x16x16bf16(pk, bv[dt], oacc[q16][dt]);
            }
        }
        __syncthreads();   // protects buf for it+2 staging
    }

    // rsacc lane mapping == oacc mapping (query = quad*4+r) -> no shuffles
    #pragma unroll
    for (int q16 = 0; q16 < 2; ++q16) {
        float inv[4];
        #pragma unroll
        for (int r = 0; r < 4; ++r)
            inv[r] = 1.0f / rsacc[q16][r];
        #pragma unroll
        for (int dt = 0; dt < 4; ++dt) {
            #pragma unroll
            for (int r = 0; r < 4; ++r) {
                int q = q0 + wq + q16 * 16 + quad * 4 + r;
                Ab[((size_t)b * SEQ + q) * DIM + h * HDIM + dt * 16 + lr] =
                    (bf16)(oacc[q16][dt][r] * inv[r]);
            }
        }
    }
}

extern "C" void kernel_launch(void* const* d_in, const int* in_sizes, int n_in,
                              void* d_out, int out_size, void* d_ws, size_t ws_size,
                              hipStream_t stream) {
    (void)in_sizes; (void)n_in; (void)out_size; (void)ws_size;
    const float* x  = (const float*)d_in[0];
    const float* Wq = (const float*)d_in[1];
    const float* Wk = (const float*)d_in[2];
    const float* Wv = (const float*)d_in[3];
    const float* Wp = (const float*)d_in[4];
    const float* bp = (const float*)d_in[5];
    float* out = (float*)d_out;

    char* ws = (char*)d_ws;
    size_t off = 0;
    auto alloc = [&](size_t bytes) {
        void* p = ws + off;
        off += (bytes + 255) & ~(size_t)255;
        return p;
    };
    const size_t big = (size_t)MROWS * DIM * sizeof(bf16);
    const size_t wsz = (size_t)DIM * DIM * sizeof(bf16);
    bf16* Xb  = (bf16*)alloc(big);
    bf16* Qb  = (bf16*)alloc(big);
    bf16* Kb  = (bf16*)alloc(big);
    bf16* Vtb = (bf16*)alloc(big);
    bf16* Wqb = (bf16*)alloc(wsz);
    bf16* Wkb = (bf16*)alloc(wsz);
    bf16* Wvb = (bf16*)alloc(wsz);
    bf16* Wpb = (bf16*)alloc(wsz);
    bf16* Ab  = Xb;   // Xb dead after projections

    const int x4 = MROWS * DIM / 4;
    cast_bf16_kernel<<<(x4 + 255) / 256, 256, 0, stream>>>(x, Xb, x4);
    const int w4 = DIM * DIM / 4;
    cast_w4_kernel<<<dim3((w4 + 255) / 256, 4), 256, 0, stream>>>(
        Wq, Wk, Wv, Wp, Wqb, Wkb, Wvb, Wpb, w4);

    qkv_gemm<<<dim3(DIM / 128, MROWS / 128, 2), 256, 0, stream>>>(Xb, Wqb, Wkb, Qb, Kb);
    vt_gemm<<<dim3(MROWS / 128, DIM / 128), 256, 0, stream>>>(Wvb, Xb, Vtb);

    attn_kernel<<<dim3(SEQ / 128, BATCH * HEADS), 256, 0, stream>>>(Qb, Kb, Vtb, Ab);

    out_gemm<<<dim3(DIM / 128, MROWS / 128), 256, 0, stream>>>(Ab, Wpb, bp, out);
}